// Round 1
// baseline (90.926 us; speedup 1.0000x reference)
//
#include <hip/hip_runtime.h>

#define HH 256
#define WW 256
#define LL 256
#define NPIX (HH*WW)      // per-batch pixels
#define NBATCH 4
#define TOTPIX (NPIX*NBATCH)

// -------- kernel 1: per-pixel level moments for centers_a = linspace(-1,1,256)
__global__ __launch_bounds__(256) void moments_kernel(
        const float* __restrict__ x,
        float* __restrict__ m0, float* __restrict__ m1, float* __restrict__ m2) {
    int i = blockIdx.x * 256 + threadIdx.x;
    float xv = x[i];
    float s0 = 0.f, s1 = 0.f, s2 = 0.f;
    const float step = 2.0f / 255.0f;
    #pragma unroll 8
    for (int j = 0; j < LL; ++j) {
        float jf = (float)j;
        float c  = fmaf(jf, step, -1.0f);
        float d  = xv - c;
        float e  = __expf(-2.0f * d * d);   // exp(-(x-c)^2 / (2*0.5^2))
        s0 += e;
        s1 = fmaf(jf, e, s1);
        s2 = fmaf(jf * jf, e, s2);
    }
    m0[i] = s0; m1[i] = s1; m2[i] = s2;
}

// -------- kernel 2: per-(combo,batch) correlation sums over valid pixel pairs
// combos 0..3: theta=0,  d={1,3,5,7}:  q=(h, w+d),   valid w < W-d
// combos 4..7: theta=45, d={1,2,4,6}:  q=(h-d, w+d), valid h>=d && w < W-d
__global__ __launch_bounds__(256) void glcm_kernel(
        const float* __restrict__ m0, const float* __restrict__ m1,
        const float* __restrict__ m2, float* __restrict__ acc) {
    const int combo = blockIdx.y;   // 0..7
    const int batch = blockIdx.z;   // 0..3
    const int w     = threadIdx.x;  // column 0..255
    const int row0  = blockIdx.x * 8;

    int d, qoff;
    bool diag;
    if (combo < 4) { const int dt[4] = {1,3,5,7}; d = dt[combo];   diag = false; }
    else           { const int dt[4] = {1,2,4,6}; d = dt[combo-4]; diag = true;  }
    qoff = diag ? (d - d * WW) : d;

    const int base = batch * NPIX;
    const bool wok = (w < WW - d);

    float num = 0.f, den = 0.f;
    #pragma unroll
    for (int r = row0; r < row0 + 8; ++r) {
        bool ok = wok && (!diag || r >= d);
        if (ok) {
            int p = base + r * WW + w;
            int q = p + qoff;
            float p0 = m0[p], p1 = m1[p], p2 = m2[p];
            float q0 = m0[q], q1 = m1[q], q2 = m2[q];
            den = fmaf(p0, q0, den);
            num = fmaf(p2, q0, num);
            num = fmaf(p0, q2, num);
            num = fmaf(-2.0f * p1, q1, num);
        }
    }

    // wave(64) reduction then cross-wave via LDS
    for (int off = 32; off > 0; off >>= 1) {
        num += __shfl_down(num, off);
        den += __shfl_down(den, off);
    }
    __shared__ float sn[4], sd[4];
    int lane = threadIdx.x & 63, wave = threadIdx.x >> 6;
    if (lane == 0) { sn[wave] = num; sd[wave] = den; }
    __syncthreads();
    if (threadIdx.x == 0) {
        float tn = sn[0] + sn[1] + sn[2] + sn[3];
        float td = sd[0] + sd[1] + sd[2] + sd[3];
        int pair = combo * 4 + batch;
        atomicAdd(&acc[pair * 2 + 0], tn);
        atomicAdd(&acc[pair * 2 + 1], td);
    }
}

// -------- kernel 3: finalize — divide, and fill theta90/135 with the closed-form constant
__global__ void finalize_kernel(const float* __restrict__ acc, float* __restrict__ out) {
    int n = threadIdx.x;           // 0..63 ; n = combo*4 + batch
    int c = n >> 2;
    float v;
    if (c < 8) {
        v = acc[n * 2 + 0] / acc[n * 2 + 1];
    } else {
        // centers_b are all -1 -> all bins equal -> contrast = sum_{jk}(j-k)^2 / L^2
        // = (2*256*5559680 - 2*32640^2)/65536
        v = 715816960.0 / 65536.0;   // 10922.666...
    }
    out[n] = v;
}

extern "C" void kernel_launch(void* const* d_in, const int* in_sizes, int n_in,
                              void* d_out, int out_size, void* d_ws, size_t ws_size,
                              hipStream_t stream) {
    const float* x = (const float*)d_in[0];
    float* out = (float*)d_out;

    float* m0  = (float*)d_ws;
    float* m1  = m0 + TOTPIX;
    float* m2  = m1 + TOTPIX;
    float* acc = m2 + TOTPIX;   // 64 floats (8 combos * 4 batches * {num,den})

    hipMemsetAsync(acc, 0, 64 * sizeof(float), stream);

    moments_kernel<<<TOTPIX / 256, 256, 0, stream>>>(x, m0, m1, m2);

    dim3 grid2(HH / 8, 8, NBATCH);
    glcm_kernel<<<grid2, 256, 0, stream>>>(m0, m1, m2, acc);

    finalize_kernel<<<1, 64, 0, stream>>>(acc, out);
}

// Round 2
// 66.277 us; speedup vs baseline: 1.3719x; 1.3719x over previous
//
#include <hip/hip_runtime.h>

#define HH 256
#define WW 256
#define NPIX (HH*WW)      // per-batch pixels
#define NBATCH 4
#define TOTPIX (NPIX*NBATCH)
#define RPB 2             // rows per glcm block
#define NBX (HH/RPB)      // 128 blocks_x
#define NPAIR 32          // 8 combos * 4 batches

// -------- kernel 1: closed-form per-pixel level moments for centers = linspace(-1,1,256)
// s0 = sum_j exp(-2(x-c_j)^2), s1 = sum_j j*e_j, s2 = sum_j j^2*e_j
// Uniform-grid Gaussian sums == midpoint-rule integrals to O(step^2) ~ 6e-5 rel:
//   sum f(c_j) ~= (1/step) * Int_{-1-h}^{1+h} f(t) dt,  h = step/2
// with Int exp(-2u^2) = sqrt(pi/8) erf(sqrt2 u),  Int u e = -e/4,  Int u^2 e = -u e/4 + I0/4.
__global__ __launch_bounds__(256) void moments_kernel(
        const float* __restrict__ x, float4* __restrict__ m) {
    int i = blockIdx.x * 256 + threadIdx.x;
    float xv = x[i];

    const float h    = 1.0f / 255.0f;      // step/2
    const float invS = 127.5f;             // 1/step
    const float K    = 0.626657068658f;    // sqrt(pi/8)
    const float SQ2  = 1.41421356237f;

    float u1 = (1.0f + h) - xv;            // upper limit (in u = t - x)
    float u0 = (-1.0f - h) - xv;           // lower limit
    float A  = SQ2 * u1;
    float B  = SQ2 * u0;

    float I0 = K * (erff(A) - erff(B));
    float eA = __expf(-A * A);             // exp(-2*u1^2)
    float eB = __expf(-B * B);             // exp(-2*u0^2)
    float I1 = 0.25f * (eB - eA);
    float I2 = 0.25f * (u0 * eB - u1 * eA) + 0.25f * I0;

    float S0  = invS * I0;                                   // sum e_j
    float Sc  = invS * fmaf(xv, I0, I1);                     // sum c_j e_j
    float Scc = invS * (xv * xv * I0 + 2.0f * xv * I1 + I2); // sum c_j^2 e_j

    float s0 = S0;
    float s1 = invS * (Sc + S0);                       // j = (c+1)/step
    float s2 = invS * invS * (Scc + 2.0f * Sc + S0);

    m[i] = make_float4(s0, s1, s2, 0.0f);
}

// -------- kernel 2: all 8 (theta,d) combos in one pass; per-block partials (no atomics)
// combos 0..3: theta=0,  d={1,3,5,7}:  q = p + d,        valid w < W-d
// combos 4..7: theta=45, d={1,2,4,6}:  q = p + d - d*W,  valid r>=d && w < W-d
__global__ __launch_bounds__(256) void glcm_kernel(
        const float4* __restrict__ m, float* __restrict__ part) {
    const int batch = blockIdx.y;
    const int w     = threadIdx.x;
    const int r0    = blockIdx.x * RPB;
    const float4* mb = m + batch * NPIX;

    float num[8] = {0,0,0,0,0,0,0,0};
    float den[8] = {0,0,0,0,0,0,0,0};
    const int d0[4]  = {1,3,5,7};
    const int d45[4] = {1,2,4,6};

    #pragma unroll
    for (int rr = 0; rr < RPB; ++rr) {
        int r   = r0 + rr;
        int idx = r * WW + w;
        float4 P = mb[idx];
        #pragma unroll
        for (int k = 0; k < 4; ++k) {
            int d = d0[k];
            if (w < WW - d) {
                float4 Q = mb[idx + d];
                den[k] = fmaf(P.x, Q.x, den[k]);
                num[k] = fmaf(P.z, Q.x, num[k]);
                num[k] = fmaf(P.x, Q.z, num[k]);
                num[k] = fmaf(-2.0f * P.y, Q.y, num[k]);
            }
        }
        #pragma unroll
        for (int k = 0; k < 4; ++k) {
            int d = d45[k];
            if (r >= d && w < WW - d) {
                float4 Q = mb[idx + d - d * WW];
                den[k+4] = fmaf(P.x, Q.x, den[k+4]);
                num[k+4] = fmaf(P.z, Q.x, num[k+4]);
                num[k+4] = fmaf(P.x, Q.z, num[k+4]);
                num[k+4] = fmaf(-2.0f * P.y, Q.y, num[k+4]);
            }
        }
    }

    // wave(64) butterfly reduce for all 16 accumulators
    #pragma unroll
    for (int off = 32; off > 0; off >>= 1) {
        #pragma unroll
        for (int k = 0; k < 8; ++k) {
            num[k] += __shfl_down(num[k], off);
            den[k] += __shfl_down(den[k], off);
        }
    }
    __shared__ float sred[4][16];
    int lane = threadIdx.x & 63, wave = threadIdx.x >> 6;
    if (lane == 0) {
        #pragma unroll
        for (int k = 0; k < 8; ++k) {
            sred[wave][k]     = num[k];
            sred[wave][k + 8] = den[k];
        }
    }
    __syncthreads();
    if (threadIdx.x < 16) {
        int k = threadIdx.x;
        float v = sred[0][k] + sred[1][k] + sred[2][k] + sred[3][k];
        if (k < 8) {
            int pair = k * 4 + batch;                      // num slot
            part[pair * NBX + blockIdx.x] = v;
        } else {
            int pair = (k - 8) * 4 + batch;                // den slot
            part[NPAIR * NBX + pair * NBX + blockIdx.x] = v;
        }
    }
}

// -------- kernel 3: finalize — sum partials, divide; theta90/135 are closed-form constant
__global__ void finalize_kernel(const float* __restrict__ part, float* __restrict__ out) {
    int n = threadIdx.x;           // 0..63 ; n = combo*4 + batch
    int c = n >> 2;
    float v;
    if (c < 8) {
        float num = 0.f, den = 0.f;
        for (int b = 0; b < NBX; ++b) {
            num += part[n * NBX + b];
            den += part[NPAIR * NBX + n * NBX + b];
        }
        v = num / den;
    } else {
        // centers_b all -1 -> all bins equal -> contrast = sum_{jk}(j-k)^2 / L^2
        v = 715816960.0 / 65536.0;   // 10922.666...
    }
    out[n] = v;
}

extern "C" void kernel_launch(void* const* d_in, const int* in_sizes, int n_in,
                              void* d_out, int out_size, void* d_ws, size_t ws_size,
                              hipStream_t stream) {
    const float* x = (const float*)d_in[0];
    float* out = (float*)d_out;

    float4* m   = (float4*)d_ws;                       // TOTPIX float4 = 4 MiB
    float* part = (float*)d_ws + TOTPIX * 4;           // 2*NPAIR*NBX floats = 32 KiB

    moments_kernel<<<TOTPIX / 256, 256, 0, stream>>>(x, m);

    dim3 grid2(NBX, NBATCH);
    glcm_kernel<<<grid2, 256, 0, stream>>>(m, part);

    finalize_kernel<<<1, 64, 0, stream>>>(part, out);
}

// Round 4
// 61.979 us; speedup vs baseline: 1.4670x; 1.0693x over previous
//
#include <hip/hip_runtime.h>

#define HH 256
#define WW 256
#define NPIX (HH*WW)
#define NBATCH 4
#define RPB 4              // P-rows owned per block
#define HALO 6             // max 45-degree displacement
#define LROWS (RPB+HALO)   // 10 rows of moments in LDS
#define NBX (HH/RPB)       // 64 blocks_x
#define NPAIR 32           // 8 combos * 4 batches

// Closed-form level moments for centers = linspace(-1,1,256), sigma = 0.5.
// s0 = sum_j exp(-2(x-c_j)^2), s1 = sum_j j*e_j, s2 = sum_j j^2*e_j.
// Uniform-grid Gaussian sums == midpoint-rule integrals to O(step^2) ~ 6e-5 rel.
__device__ __forceinline__ void moments(float xv, float& s0, float& s1, float& s2) {
    const float h    = 1.0f / 255.0f;      // step/2
    const float invS = 127.5f;             // 1/step
    const float K    = 0.626657068658f;    // sqrt(pi/8)
    const float SQ2  = 1.41421356237f;

    float u1 = (1.0f + h) - xv;
    float u0 = (-1.0f - h) - xv;
    float A  = SQ2 * u1;
    float B  = SQ2 * u0;

    float I0 = K * (erff(A) - erff(B));
    float eA = __expf(-A * A);
    float eB = __expf(-B * B);
    float I1 = 0.25f * (eB - eA);
    float I2 = 0.25f * (u0 * eB - u1 * eA) + 0.25f * I0;

    float S0  = invS * I0;
    float Sc  = invS * fmaf(xv, I0, I1);
    float Scc = invS * (xv * xv * I0 + 2.0f * xv * I1 + I2);

    s0 = S0;
    s1 = invS * (Sc + S0);
    s2 = invS * invS * (Scc + 2.0f * Sc + S0);
}

// Fused: per-tile moments into LDS + all 8 (theta,d) pair sums -> per-block partials.
// combos 0..3: theta=0,  d={1,3,5,7}: Q=(r, w+d),   valid w<W-d
// combos 4..7: theta=45, d={1,2,4,6}: Q=(r-d, w+d), valid r>=d && w<W-d
__global__ __launch_bounds__(256) void fused_kernel(const float* __restrict__ x,
                                                    float* __restrict__ part) {
    __shared__ float ls0[LROWS][WW];
    __shared__ float ls1[LROWS][WW];
    __shared__ float ls2[LROWS][WW];
    __shared__ float sred[4][16];

    const int w     = threadIdx.x;          // column (lane = column -> stride-1 LDS)
    const int bx    = blockIdx.x;
    const int batch = blockIdx.y;
    const int r0    = bx * RPB;
    const float* xb = x + batch * NPIX;

    #pragma unroll
    for (int i = 0; i < LROWS; ++i) {
        int g = r0 - HALO + i;
        float s0 = 0.f, s1 = 0.f, s2 = 0.f;
        if (g >= 0) moments(xb[g * WW + w], s0, s1, s2);
        ls0[i][w] = s0; ls1[i][w] = s1; ls2[i][w] = s2;
    }
    __syncthreads();

    const int d0t[4]  = {1, 3, 5, 7};
    const int d45t[4] = {1, 2, 4, 6};
    float num[8] = {0,0,0,0,0,0,0,0};
    float den[8] = {0,0,0,0,0,0,0,0};

    #pragma unroll
    for (int rr = 0; rr < RPB; ++rr) {
        int lr = rr + HALO;
        int r  = r0 + rr;
        float P0 = ls0[lr][w], P1 = ls1[lr][w], P2 = ls2[lr][w];
        #pragma unroll
        for (int k = 0; k < 4; ++k) {
            int d = d0t[k];
            if (w < WW - d) {
                float Q0 = ls0[lr][w + d], Q1 = ls1[lr][w + d], Q2 = ls2[lr][w + d];
                den[k] = fmaf(P0, Q0, den[k]);
                num[k] = fmaf(P2, Q0, num[k]);
                num[k] = fmaf(P0, Q2, num[k]);
                num[k] = fmaf(-2.0f * P1, Q1, num[k]);
            }
        }
        #pragma unroll
        for (int k = 0; k < 4; ++k) {
            int d = d45t[k];
            if (r >= d && w < WW - d) {
                float Q0 = ls0[lr - d][w + d], Q1 = ls1[lr - d][w + d], Q2 = ls2[lr - d][w + d];
                den[k + 4] = fmaf(P0, Q0, den[k + 4]);
                num[k + 4] = fmaf(P2, Q0, num[k + 4]);
                num[k + 4] = fmaf(P0, Q2, num[k + 4]);
                num[k + 4] = fmaf(-2.0f * P1, Q1, num[k + 4]);
            }
        }
    }

    // wave(64) butterfly, then cross-wave combine via LDS
    #pragma unroll
    for (int off = 32; off > 0; off >>= 1) {
        #pragma unroll
        for (int k = 0; k < 8; ++k) {
            num[k] += __shfl_down(num[k], off);
            den[k] += __shfl_down(den[k], off);
        }
    }
    int lane = threadIdx.x & 63, wave = threadIdx.x >> 6;
    if (lane == 0) {
        #pragma unroll
        for (int k = 0; k < 8; ++k) { sred[wave][k] = num[k]; sred[wave][k + 8] = den[k]; }
    }
    __syncthreads();
    if (threadIdx.x < 16) {
        int k = threadIdx.x;
        float v = sred[0][k] + sred[1][k] + sred[2][k] + sred[3][k];
        int pair = (k & 7) * 4 + batch;
        int off  = (k < 8) ? 0 : NPAIR * NBX;
        part[off + pair * NBX + bx] = v;
    }
}

// Finalize: 4 lanes per output sum the 64 partials; theta90/135 are the closed-form constant.
__global__ void finalize_kernel(const float* __restrict__ part, float* __restrict__ out) {
    int t = threadIdx.x;          // 0..255
    int p = t >> 2;               // output index n = combo*4 + batch, 0..63
    int c = t & 3;                // chunk of 16 partials
    float num = 0.f, den = 0.f;
    if (p < NPAIR) {
        #pragma unroll
        for (int b = 0; b < 16; ++b) {
            num += part[p * NBX + c * 16 + b];
            den += part[NPAIR * NBX + p * NBX + c * 16 + b];
        }
    }
    num += __shfl_down(num, 2); num += __shfl_down(num, 1);
    den += __shfl_down(den, 2); den += __shfl_down(den, 1);
    if (c == 0) {
        // centers_b all -1 -> all bins equal -> contrast = sum_{jk}(j-k)^2 / L^2
        out[p] = (p < NPAIR) ? (num / den) : (float)(715816960.0 / 65536.0);
    }
}

extern "C" void kernel_launch(void* const* d_in, const int* in_sizes, int n_in,
                              void* d_out, int out_size, void* d_ws, size_t ws_size,
                              hipStream_t stream) {
    const float* x = (const float*)d_in[0];
    float* out = (float*)d_out;
    float* part = (float*)d_ws;   // 2 * NPAIR * NBX floats = 16 KiB, fully overwritten

    dim3 g1(NBX, NBATCH);
    fused_kernel<<<g1, 256, 0, stream>>>(x, part);
    finalize_kernel<<<1, 256, 0, stream>>>(part, out);
}